// Round 17
// baseline (303.680 us; speedup 1.0000x reference)
//
#include <hip/hip_runtime.h>
#include <math.h>

#define BB 2
#define NN 512
#define DD 128
#define HH 8
#define DKK 16
#define TR 64            // tile rows
#define NT (NN / TR)     // 8 tiles per (b,n)
#define ETS 516          // padded ET row stride (%32=4 -> conflict-free RMW; %4=0 -> b128 ok)

typedef __attribute__((ext_vector_type(8))) short short8;
typedef __attribute__((ext_vector_type(4))) float f32x4;

__device__ __forceinline__ float dot4(float4 a, float4 b) {
    return a.x*b.x + a.y*b.y + a.z*b.z + a.w*b.w;
}
// RNE f32 -> bf16 pack (a in low, b in high)
__device__ __forceinline__ unsigned pk_bf16(float a, float b) {
    unsigned ua = __float_as_uint(a), ub = __float_as_uint(b);
    ua = (ua + 0x7FFFu + ((ua >> 16) & 1u)) >> 16;
    ub = (ub + 0x7FFFu + ((ub >> 16) & 1u)) >> 16;
    return ua | (ub << 16);
}

// ---- all-VALU / low-LDS cross-lane sum over 64 lanes (R8-proven helpers) ----
template<int CTRL>
__device__ __forceinline__ float dpp_sum(float x) {
    return x + __int_as_float(__builtin_amdgcn_mov_dpp(
        __float_as_int(x), CTRL, 0xF, 0xF, true));
}
__device__ __forceinline__ float pl16_sum(float x) {
#if __has_builtin(__builtin_amdgcn_permlane16_swap)
    auto p = __builtin_amdgcn_permlane16_swap(__float_as_int(x),
                                              __float_as_int(x), false, false);
    return __int_as_float(p[0]) + __int_as_float(p[1]);
#else
    return x + __shfl_xor(x, 16, 64);
#endif
}
__device__ __forceinline__ float pl32_sum(float x) {
#if __has_builtin(__builtin_amdgcn_permlane32_swap)
    auto p = __builtin_amdgcn_permlane32_swap(__float_as_int(x),
                                              __float_as_int(x), false, false);
    return __int_as_float(p[0]) + __int_as_float(p[1]);
#else
    return x + __shfl_xor(x, 32, 64);
#endif
}
__device__ __forceinline__ float red64(float x) {
    x = dpp_sum<0xB1>(x);            // xor 1
    x = dpp_sum<0x4E>(x);            // xor 2
    x += __shfl_xor(x, 4, 64);       // xor 4
    x += __shfl_xor(x, 8, 64);       // xor 8
    x = pl16_sum(x);                 // xor 16
    x = pl32_sum(x);                 // xor 32
    return x;
}

// ---------------- Kernel 1: QKV projection + W_egT staging ----------------
__global__ __launch_bounds__(128)
void qkv_kernel(const float* __restrict__ n_in,
                const float* __restrict__ W_qkv,
                const float* __restrict__ W_g,
                const float* __restrict__ W_e,
                float* __restrict__ Qw, float* __restrict__ Kw,
                float* __restrict__ Vw, float* __restrict__ WegT)
{
    const int bid = blockIdx.x;
    if (bid >= BB * NN) {                    // 16 trailing blocks: WegT[col][d]
        const int col = bid - BB * NN;
        const int t = threadIdx.x;
        WegT[col * DD + t] = (col < 8) ? W_e[t * HH + col]
                                       : W_g[t * HH + (col - 8)];
        return;
    }
    __shared__ float nrow[DD];
    const int bn = bid;
    const int b  = bn >> 9;
    const int nr = bn & 511;
    const int t  = threadIdx.x;
    nrow[t] = n_in[(size_t)bn * DD + t];
    __syncthreads();
    const int h = t >> 4, dk = t & 15;
    const size_t dst = ((size_t)(b * HH + h) * NN + nr) * DKK + dk;
    float accq = 0.f, acck = 0.f, accv = 0.f;
    #pragma unroll 8
    for (int d = 0; d < DD; ++d) {
        const float nv = nrow[d];
        const float* wr = W_qkv + (size_t)d * 3 * DD;
        accq += nv * wr[t];
        acck += nv * wr[t + 128];
        accv += nv * wr[t + 256];
    }
    Qw[dst] = accq;
    Kw[dst] = acck;
    Vw[dst] = accv;
}

// ---------------- Kernel 2: fused QK + E/G (MFMA) + e_out + softmax/AV + n_out
// One block per (b,n), 512 threads = 8 waves. TR=64, parity-alternating MFMA
// groups (R13-proven). TWO register prefetch sets -> 2 tiles in flight.
__global__ __attribute__((amdgpu_flat_work_group_size(512, 512),
                          amdgpu_waves_per_eu(8)))
void eg_kernel(const float* __restrict__ e,
               const float* __restrict__ WegT,
               const float* __restrict__ O_e,
               const float* __restrict__ Qw,
               const float* __restrict__ Kw,
               const float* __restrict__ Vw,
               const float* __restrict__ O_n,
               float* __restrict__ n_out,
               float* __restrict__ e_out)
{
    __shared__ __align__(16) uint4 ebuf4[TR * 16];   // 16KB bf16 tile (single)
    __shared__ __align__(16) float ET[HH * ETS];     // 16.5KB persistent _E [h][m]
    __shared__ float Gred[64];
    __shared__ float dc[HH];
    __shared__ __align__(16) float vout[DD];

    const int t    = threadIdx.x;
    const int bn   = blockIdx.x;
    const int b    = bn >> 9;
    const int nr   = bn & 511;
    const int wq   = t >> 6;
    const int lane = t & 63;
    const int c    = lane & 15;      // MFMA C/D col (= W col / head)
    const int mq   = lane >> 4;      // C/D row group; also A/B k-group
    const int wgrp = wq & 3;         // m-block within tile
    const int wpar = wq >> 2;        // group parity (0: even tiles, 1: odd)
    const int c4o  = t & 31;         // e_out float4 column
    const int mr0  = t >> 5;         // e_out row-group base 0..15

    const float4* __restrict__ e4    = (const float4*)e + (size_t)bn * NN * 32;
    const float4* __restrict__ WegT4 = (const float4*)WegT;

    // ---- B fragments: W[col=c][k] -> bf16, 4 k-steps (16 VGPR) ----
    short8 wB[4];
    #pragma unroll
    for (int kb = 0; kb < 4; ++kb) {
        const float4 wa = WegT4[c * 32 + kb * 8 + mq * 2];
        const float4 wb = WegT4[c * 32 + kb * 8 + mq * 2 + 1];
        uint4 u;
        u.x = pk_bf16(wa.x, wa.y); u.y = pk_bf16(wa.z, wa.w);
        u.z = pk_bf16(wb.x, wb.y); u.w = pk_bf16(wb.z, wb.w);
        wB[kb] = *(short8*)&u;
    }

    // two prefetch register sets (16 VGPR each)
    float4 pa0, pb0, pa1, pb1;   // set 0 (even tiles)
    float4 qa0, qb0, qa1, qb1;   // set 1 (odd tiles)

    #define LOAD_SET0(tile)                                                   \
    {                                                                         \
        const float4* __restrict__ sp = e4 + (size_t)(tile) * 2048 + 2 * t;   \
        pa0 = sp[0];    pb0 = sp[1];                                          \
        pa1 = sp[1024]; pb1 = sp[1025];                                       \
    }
    #define LOAD_SET1(tile)                                                   \
    {                                                                         \
        const float4* __restrict__ sp = e4 + (size_t)(tile) * 2048 + 2 * t;   \
        qa0 = sp[0];    qb0 = sp[1];                                          \
        qa1 = sp[1024]; qb1 = sp[1025];                                       \
    }
    #define STAGE_W1(U, A, Bv)                                                \
    {                                                                         \
        const int u_ = (U), ms = u_ >> 4, ck = u_ & 15;                       \
        uint4 x;                                                              \
        x.x = pk_bf16(A.x, A.y);   x.y = pk_bf16(A.z, A.w);                   \
        x.z = pk_bf16(Bv.x, Bv.y); x.w = pk_bf16(Bv.z, Bv.w);                 \
        ebuf4[ms * 16 + (ck ^ (ms & 15))] = x;                                \
    }
    #define WRITE_SET0() { STAGE_W1(t, pa0, pb0); STAGE_W1(t + 512, pa1, pb1); }
    #define WRITE_SET1() { STAGE_W1(t, qa0, qb0); STAGE_W1(t + 512, qa1, qb1); }

    float ga0 = 0.f, ga1 = 0.f, ga2 = 0.f, ga3 = 0.f;

    // ---- prologue ----
    LOAD_SET0(0);                       // tile 0 in flight

    {   // wave wq = head h; clamped QK scores -> ET[h][m] (K panel L2-resident)
        const int h = wq;
        const float4* __restrict__ qp =
            (const float4*)(Qw + ((size_t)(b * HH + h) * NN + nr) * DKK);
        const float4 q0 = qp[0], q1 = qp[1], q2 = qp[2], q3 = qp[3];
        const float4* __restrict__ kb =
            (const float4*)(Kw + ((size_t)(b * HH + h) * NN) * DKK);
        #pragma unroll
        for (int k = 0; k < 8; ++k) {
            const int m = k * 64 + lane;
            float s = dot4(q0, kb[m * 4 + 0]) + dot4(q1, kb[m * 4 + 1])
                    + dot4(q2, kb[m * 4 + 2]) + dot4(q3, kb[m * 4 + 3]);
            s *= 0.25f;
            ET[h * ETS + m] = fminf(5.f, fmaxf(-5.f, s));
        }
    }

    LOAD_SET1(1);                       // tile 1 in flight
    WRITE_SET0();                       // tile 0 -> ebuf (waits set0 only)
    LOAD_SET0(2);                       // tile 2 in flight
    asm volatile("s_waitcnt lgkmcnt(0)" ::: "memory");
    __builtin_amdgcn_s_barrier();

    #pragma unroll
    for (int tt = 0; tt < NT; ++tt) {
        // ---- MFMA: tile parity selects the active 4-wave group ----
        if (wpar == (tt & 1)) {
            const int mrow = wgrp * 16 + c;
            f32x4 acc = {0.f, 0.f, 0.f, 0.f};
            #pragma unroll
            for (int kb = 0; kb < 4; ++kb) {
                const int ck = kb * 4 + mq;
                uint4 av = ebuf4[mrow * 16 + (ck ^ (mrow & 15))];
                acc = __builtin_amdgcn_mfma_f32_16x16x32_bf16(
                          *(short8*)&av, wB[kb], acc, 0, 0, 0);
            }
            const int mloc = tt * TR + wgrp * 16 + mq * 4;
            if (c < 8) {
                float4 prev = *(float4*)&ET[c * ETS + mloc];
                prev.x += acc[0]; prev.y += acc[1];
                prev.z += acc[2]; prev.w += acc[3];
                *(float4*)&ET[c * ETS + mloc] = prev;
            } else {
                ga0 += 1.f / (1.f + __expf(-acc[0]));
                ga1 += 1.f / (1.f + __expf(-acc[1]));
                ga2 += 1.f / (1.f + __expf(-acc[2]));
                ga3 += 1.f / (1.f + __expf(-acc[3]));
            }
        }
        asm volatile("s_waitcnt lgkmcnt(0)" ::: "memory");
        __builtin_amdgcn_s_barrier();   // ebuf reads done; ET RMW ordered

        // ---- refill ebuf for tile tt+1; reissue loads 3 tiles ahead ----
        if (tt + 1 < NT) {
            if ((tt + 1) & 1) {         // odd tile -> set 1
                WRITE_SET1();
                if (tt + 3 < NT) LOAD_SET1(tt + 3);
            } else {                    // even tile -> set 0
                WRITE_SET0();
                if (tt + 3 < NT) LOAD_SET0(tt + 3);
            }
            asm volatile("s_waitcnt lgkmcnt(0)" ::: "memory");
            __builtin_amdgcn_s_barrier();
        }
    }

    // ---- G reduction -> dyn_cent ----
    if (c >= 8) {
        float s = ga0 + ga1 + ga2 + ga3;
        s += __shfl_xor(s, 16, 64);
        s += __shfl_xor(s, 32, 64);
        if (lane < 16) Gred[wq * 8 + (c - 8)] = s;
    }
    __syncthreads();
    if (t < 8) {
        float s = 0.f;
        #pragma unroll
        for (int w = 0; w < 8; ++w) s += Gred[w * 8 + t];
        dc[t] = log1pf(s);
    }
    __syncthreads();

    // ---- e_out: b128 ET reads, 4-row groups; oe loaded here (tail-local) ----
    {
        float4 oe[8];
        #pragma unroll
        for (int h = 0; h < 8; ++h)
            oe[h] = ((const float4*)O_e)[h * 32 + c4o];
        float4* __restrict__ out4 = (float4*)e_out + (size_t)bn * NN * 32;
        #pragma unroll 2
        for (int g = 0; g < 8; ++g) {
            const int m0 = mr0 * 32 + g * 4;
            float4 r0{0,0,0,0}, r1{0,0,0,0}, r2{0,0,0,0}, r3{0,0,0,0};
            #pragma unroll
            for (int h = 0; h < 8; ++h) {
                const float4 ev = *(const float4*)&ET[h * ETS + m0]; // broadcast b128
                r0.x += ev.x*oe[h].x; r0.y += ev.x*oe[h].y;
                r0.z += ev.x*oe[h].z; r0.w += ev.x*oe[h].w;
                r1.x += ev.y*oe[h].x; r1.y += ev.y*oe[h].y;
                r1.z += ev.y*oe[h].z; r1.w += ev.y*oe[h].w;
                r2.x += ev.z*oe[h].x; r2.y += ev.z*oe[h].y;
                r2.z += ev.z*oe[h].z; r2.w += ev.z*oe[h].w;
                r3.x += ev.w*oe[h].x; r3.y += ev.w*oe[h].y;
                r3.z += ev.w*oe[h].z; r3.w += ev.w*oe[h].w;
            }
            out4[(m0 + 0) * 32 + c4o] = r0;
            out4[(m0 + 1) * 32 + c4o] = r1;
            out4[(m0 + 2) * 32 + c4o] = r2;
            out4[(m0 + 3) * 32 + c4o] = r3;
        }
    }

    // ---- softmax + AV: wave wq owns head wq; lane-per-m, vals reused ----
    {
        const int h = wq;
        float vals[8];
        float rmax = -1e30f;
        #pragma unroll
        for (int k = 0; k < 8; ++k) {
            vals[k] = ET[h * ETS + k * 64 + lane];
            rmax = fmaxf(rmax, vals[k]);
        }
        #pragma unroll
        for (int off = 32; off >= 1; off >>= 1)
            rmax = fmaxf(rmax, __shfl_xor(rmax, off, 64));
        float sum = 0.f;
        #pragma unroll
        for (int k = 0; k < 8; ++k) {
            vals[k] = __expf(vals[k] - rmax);   // keep P in regs
            sum += vals[k];
        }
        #pragma unroll
        for (int off = 32; off >= 1; off >>= 1)
            sum += __shfl_xor(sum, off, 64);
        const float factor = dc[h] / sum;

        const float4* __restrict__ vb4 =
            (const float4*)(Vw + ((size_t)(b * HH + h) * NN) * DKK);
        float4 av0{0,0,0,0}, av1{0,0,0,0}, av2{0,0,0,0}, av3{0,0,0,0};
        #pragma unroll
        for (int k = 0; k < 8; ++k) {
            const int m = k * 64 + lane;
            const float p = vals[k];
            const float4 v0 = vb4[m * 4 + 0];
            const float4 v1 = vb4[m * 4 + 1];
            const float4 v2 = vb4[m * 4 + 2];
            const float4 v3 = vb4[m * 4 + 3];
            av0.x += p*v0.x; av0.y += p*v0.y; av0.z += p*v0.z; av0.w += p*v0.w;
            av1.x += p*v1.x; av1.y += p*v1.y; av1.z += p*v1.z; av1.w += p*v1.w;
            av2.x += p*v2.x; av2.y += p*v2.y; av2.z += p*v2.z; av2.w += p*v2.w;
            av3.x += p*v3.x; av3.y += p*v3.y; av3.z += p*v3.z; av3.w += p*v3.w;
        }
        av0.x = red64(av0.x); av0.y = red64(av0.y);
        av0.z = red64(av0.z); av0.w = red64(av0.w);
        av1.x = red64(av1.x); av1.y = red64(av1.y);
        av1.z = red64(av1.z); av1.w = red64(av1.w);
        av2.x = red64(av2.x); av2.y = red64(av2.y);
        av2.z = red64(av2.z); av2.w = red64(av2.w);
        av3.x = red64(av3.x); av3.y = red64(av3.y);
        av3.z = red64(av3.z); av3.w = red64(av3.w);
        if (lane == 0) {
            float* vo = &vout[h * DKK];
            vo[0]  = av0.x * factor; vo[1]  = av0.y * factor;
            vo[2]  = av0.z * factor; vo[3]  = av0.w * factor;
            vo[4]  = av1.x * factor; vo[5]  = av1.y * factor;
            vo[6]  = av1.z * factor; vo[7]  = av1.w * factor;
            vo[8]  = av2.x * factor; vo[9]  = av2.y * factor;
            vo[10] = av2.z * factor; vo[11] = av2.w * factor;
            vo[12] = av3.x * factor; vo[13] = av3.y * factor;
            vo[14] = av3.z * factor; vo[15] = av3.w * factor;
        }
    }
    __syncthreads();

    // ---- n_out = vout @ O_n ----
    if (t < DD) {
        float a3 = 0.f;
        #pragma unroll 4
        for (int d = 0; d < DD; ++d) a3 += vout[d] * O_n[d * DD + t];
        n_out[(size_t)bn * DD + t] = a3;
    }
    #undef LOAD_SET0
    #undef LOAD_SET1
    #undef STAGE_W1
    #undef WRITE_SET0
    #undef WRITE_SET1
}

extern "C" void kernel_launch(void* const* d_in, const int* in_sizes, int n_in,
                              void* d_out, int out_size, void* d_ws, size_t ws_size,
                              hipStream_t stream)
{
    const float* n_ptr = (const float*)d_in[0];
    const float* e     = (const float*)d_in[1];
    const float* W_qkv = (const float*)d_in[2];
    const float* O_n   = (const float*)d_in[3];
    const float* W_g   = (const float*)d_in[4];
    const float* W_e   = (const float*)d_in[5];
    const float* O_e   = (const float*)d_in[6];

    float* n_out = (float*)d_out;
    float* e_out = n_out + (size_t)BB * NN * DD;

    float* Qw   = (float*)d_ws;                          // 3 x 0.5MB
    float* Kw   = Qw + (size_t)BB * HH * NN * DKK;
    float* Vw   = Kw + (size_t)BB * HH * NN * DKK;
    float* WegT = Vw + (size_t)BB * HH * NN * DKK;       // 8KB

    qkv_kernel<<<BB * NN + 16, 128, 0, stream>>>(n_ptr, W_qkv, W_g, W_e,
                                                 Qw, Kw, Vw, WegT);
    eg_kernel<<<BB * NN, 512, 0, stream>>>(e, WegT, O_e, Qw, Kw, Vw, O_n,
                                           n_out, e_out);
}

// Round 18
// 178.088 us; speedup vs baseline: 1.7052x; 1.7052x over previous
//
#include <hip/hip_runtime.h>
#include <math.h>

#define BB 2
#define NN 512
#define DD 128
#define HH 8
#define DKK 16
#define TR 128           // tile rows
#define NT (NN / TR)     // 4 tiles per (b,n)
#define ETS 516          // padded ET row stride (%32=4 -> conflict-free RMW; %4=0 -> b128 ok)

typedef __attribute__((ext_vector_type(8))) short short8;
typedef __attribute__((ext_vector_type(4))) float f32x4;

__device__ __forceinline__ float dot4(float4 a, float4 b) {
    return a.x*b.x + a.y*b.y + a.z*b.z + a.w*b.w;
}
// RNE f32 -> bf16 pack (a in low, b in high)
__device__ __forceinline__ unsigned pk_bf16(float a, float b) {
    unsigned ua = __float_as_uint(a), ub = __float_as_uint(b);
    ua = (ua + 0x7FFFu + ((ua >> 16) & 1u)) >> 16;
    ub = (ub + 0x7FFFu + ((ub >> 16) & 1u)) >> 16;
    return ua | (ub << 16);
}

// ---------------- Kernel 1: QKV projection + W_egT staging ----------------
__global__ __launch_bounds__(128)
void qkv_kernel(const float* __restrict__ n_in,
                const float* __restrict__ W_qkv,
                const float* __restrict__ W_g,
                const float* __restrict__ W_e,
                float* __restrict__ Qw, float* __restrict__ Kw,
                float* __restrict__ Vw, float* __restrict__ WegT)
{
    const int bid = blockIdx.x;
    if (bid >= BB * NN) {                    // 16 trailing blocks: WegT[col][d]
        const int col = bid - BB * NN;
        const int t = threadIdx.x;
        WegT[col * DD + t] = (col < 8) ? W_e[t * HH + col]
                                       : W_g[t * HH + (col - 8)];
        return;
    }
    __shared__ float nrow[DD];
    const int bn = bid;
    const int b  = bn >> 9;
    const int nr = bn & 511;
    const int t  = threadIdx.x;
    nrow[t] = n_in[(size_t)bn * DD + t];
    __syncthreads();
    const int h = t >> 4, dk = t & 15;
    const size_t dst = ((size_t)(b * HH + h) * NN + nr) * DKK + dk;
    float accq = 0.f, acck = 0.f, accv = 0.f;
    #pragma unroll 8
    for (int d = 0; d < DD; ++d) {
        const float nv = nrow[d];
        const float* wr = W_qkv + (size_t)d * 3 * DD;
        accq += nv * wr[t];
        acck += nv * wr[t + 128];
        accv += nv * wr[t + 256];
    }
    Qw[dst] = accq;
    Kw[dst] = acck;
    Vw[dst] = accv;
}

// ---------------- Kernel 2: fully fused QK + E/G (MFMA) + e_out + softmax/AV
// + n_out. One block per (b,n), 512 threads = 8 waves. R11 loop structure
// (VGPR-64-proven); tail optimized: b128 e_out reads, P-writeback (8 exp).
__global__ __attribute__((amdgpu_flat_work_group_size(512, 512),
                          amdgpu_waves_per_eu(2, 4)))
void eg_kernel(const float* __restrict__ e,
               const float* __restrict__ WegT,
               const float* __restrict__ O_e,
               const float* __restrict__ Qw,
               const float* __restrict__ Kw,
               const float* __restrict__ Vw,
               const float* __restrict__ O_n,
               float* __restrict__ n_out,
               float* __restrict__ e_out)
{
    __shared__ __align__(16) uint4 ebuf4[TR * 16];   // 32KB bf16 tile (single)
    __shared__ __align__(16) float ET[HH * ETS];     // 16.5KB persistent _E [h][m]
    __shared__ float Gred[64];
    __shared__ float dc[HH];
    __shared__ __align__(16) float vout[DD];

    const int t    = threadIdx.x;
    const int bn   = blockIdx.x;
    const int b    = bn >> 9;
    const int nr   = bn & 511;
    const int wq   = t >> 6;
    const int lane = t & 63;
    const int c    = lane & 15;      // MFMA C/D col (= W col / head)
    const int mq   = lane >> 4;      // C/D row group; also A/B k-group
    const int c4o  = t & 31;         // e_out float4 column
    const int mr0  = t >> 5;         // e_out row-group base 0..15

    const float4* __restrict__ e4    = (const float4*)e + (size_t)bn * NN * 32;
    const float4* __restrict__ WegT4 = (const float4*)WegT;

    // ---- B fragments: W[col=c][k] -> bf16, 4 k-steps (16 VGPR) ----
    short8 wB[4];
    #pragma unroll
    for (int kb = 0; kb < 4; ++kb) {
        const float4 wa = WegT4[c * 32 + kb * 8 + mq * 2];
        const float4 wb = WegT4[c * 32 + kb * 8 + mq * 2 + 1];
        uint4 u;
        u.x = pk_bf16(wa.x, wa.y); u.y = pk_bf16(wa.z, wa.w);
        u.z = pk_bf16(wb.x, wb.y); u.w = pk_bf16(wb.z, wb.w);
        wB[kb] = *(short8*)&u;
    }

    // stage-load regs: 8 float4 (32 VGPR)
    float4 pa0, pa1, pa2, pa3, pb0, pb1, pb2, pb3;

    #define STAGE_LOAD(tile)                                                  \
    {                                                                         \
        const float4* __restrict__ sp = e4 + (size_t)(tile) * 4096 + 2 * t;   \
        pa0 = sp[0];    pb0 = sp[1];                                          \
        pa1 = sp[1024]; pb1 = sp[1025];                                       \
        pa2 = sp[2048]; pb2 = sp[2049];                                       \
        pa3 = sp[3072]; pb3 = sp[3073];                                       \
    }
    #define STAGE_WRITE(P, A, B)                                              \
    {                                                                         \
        const int ms = (P) * 32 + (t >> 4), ck = t & 15;                      \
        uint4 u;                                                              \
        u.x = pk_bf16(A.x, A.y); u.y = pk_bf16(A.z, A.w);                     \
        u.z = pk_bf16(B.x, B.y); u.w = pk_bf16(B.z, B.w);                     \
        ebuf4[ms * 16 + (ck ^ (ms & 15))] = u;                                \
    }
    #define STAGE_WRITE_ALL()                                                 \
    {                                                                         \
        STAGE_WRITE(0, pa0, pb0); STAGE_WRITE(1, pa1, pb1);                   \
        STAGE_WRITE(2, pa2, pb2); STAGE_WRITE(3, pa3, pb3);                   \
    }

    float ga0 = 0.f, ga1 = 0.f, ga2 = 0.f, ga3 = 0.f;

    // ---- prologue: issue tile-0 e loads (HBM), then QK scores (L2) ----
    STAGE_LOAD(0);

    {   // wave wq = head h; clamped scores -> ET[h][m]
        const int h = wq;
        const float4* __restrict__ qp =
            (const float4*)(Qw + ((size_t)(b * HH + h) * NN + nr) * DKK);
        const float4 q0 = qp[0], q1 = qp[1], q2 = qp[2], q3 = qp[3];
        const float4* __restrict__ kb =
            (const float4*)(Kw + ((size_t)(b * HH + h) * NN) * DKK);
        #pragma unroll
        for (int k = 0; k < 8; ++k) {
            const int m = k * 64 + lane;
            float s = dot4(q0, kb[m * 4 + 0]) + dot4(q1, kb[m * 4 + 1])
                    + dot4(q2, kb[m * 4 + 2]) + dot4(q3, kb[m * 4 + 3]);
            s *= 0.25f;
            ET[h * ETS + m] = fminf(5.f, fmaxf(-5.f, s));
        }
    }

    STAGE_WRITE_ALL();
    asm volatile("s_waitcnt lgkmcnt(0)" ::: "memory");
    __builtin_amdgcn_s_barrier();

    #pragma unroll
    for (int tt = 0; tt < NT; ++tt) {
        // prefetch next tile into regs (stays in flight across the MFMA)
        if (tt + 1 < NT) STAGE_LOAD(tt + 1);

        // ---- MFMA: E/G for this wave's 16 rows x 16 cols ----
        const int mrow = wq * 16 + c;
        f32x4 acc = {0.f, 0.f, 0.f, 0.f};
        #pragma unroll
        for (int kb = 0; kb < 4; ++kb) {
            const int ck = kb * 4 + mq;
            uint4 av = ebuf4[mrow * 16 + (ck ^ (mrow & 15))];
            acc = __builtin_amdgcn_mfma_f32_16x16x32_bf16(
                      *(short8*)&av, wB[kb], acc, 0, 0, 0);
        }

        // ---- epilogue: _E = acc + clamped_score (LDS RMW) / G accumulate ----
        const int mloc = tt * TR + wq * 16 + mq * 4;
        if (c < 8) {
            float4 prev = *(float4*)&ET[c * ETS + mloc];
            prev.x += acc[0]; prev.y += acc[1];
            prev.z += acc[2]; prev.w += acc[3];
            *(float4*)&ET[c * ETS + mloc] = prev;
        } else {
            ga0 += 1.f / (1.f + __expf(-acc[0]));
            ga1 += 1.f / (1.f + __expf(-acc[1]));
            ga2 += 1.f / (1.f + __expf(-acc[2]));
            ga3 += 1.f / (1.f + __expf(-acc[3]));
        }
        asm volatile("s_waitcnt lgkmcnt(0)" ::: "memory");
        __builtin_amdgcn_s_barrier();   // ebuf reads done; ET writes visible

        // ---- refill ebuf from prefetched regs ----
        if (tt + 1 < NT) {
            STAGE_WRITE_ALL();          // compiler waits the prefetch vmcnt
            asm volatile("s_waitcnt lgkmcnt(0)" ::: "memory");
            __builtin_amdgcn_s_barrier();
        }
    }

    // ---- G reduction -> dyn_cent ----
    if (c >= 8) {
        float s = ga0 + ga1 + ga2 + ga3;
        s += __shfl_xor(s, 16, 64);
        s += __shfl_xor(s, 32, 64);
        if (lane < 16) Gred[wq * 8 + (c - 8)] = s;
    }
    __syncthreads();
    if (t < 8) {
        float s = 0.f;
        #pragma unroll
        for (int w = 0; w < 8; ++w) s += Gred[w * 8 + t];
        dc[t] = log1pf(s);
    }
    __syncthreads();

    // ---- e_out: b128 ET reads (4-row groups), oe tail-local ----
    {
        float4 oe[8];
        #pragma unroll
        for (int h = 0; h < 8; ++h)
            oe[h] = ((const float4*)O_e)[h * 32 + c4o];
        float4* __restrict__ out4 = (float4*)e_out + (size_t)bn * NN * 32;
        #pragma unroll 2
        for (int g = 0; g < 8; ++g) {
            const int m0 = mr0 * 32 + g * 4;
            float4 r0{0,0,0,0}, r1{0,0,0,0}, r2{0,0,0,0}, r3{0,0,0,0};
            #pragma unroll
            for (int h = 0; h < 8; ++h) {
                const float4 ev = *(const float4*)&ET[h * ETS + m0]; // b128, 2-way bcast
                r0.x += ev.x*oe[h].x; r0.y += ev.x*oe[h].y;
                r0.z += ev.x*oe[h].z; r0.w += ev.x*oe[h].w;
                r1.x += ev.y*oe[h].x; r1.y += ev.y*oe[h].y;
                r1.z += ev.y*oe[h].z; r1.w += ev.y*oe[h].w;
                r2.x += ev.z*oe[h].x; r2.y += ev.z*oe[h].y;
                r2.z += ev.z*oe[h].z; r2.w += ev.z*oe[h].w;
                r3.x += ev.w*oe[h].x; r3.y += ev.w*oe[h].y;
                r3.z += ev.w*oe[h].z; r3.w += ev.w*oe[h].w;
            }
            out4[(m0 + 0) * 32 + c4o] = r0;
            out4[(m0 + 1) * 32 + c4o] = r1;
            out4[(m0 + 2) * 32 + c4o] = r2;
            out4[(m0 + 3) * 32 + c4o] = r3;
        }
    }
    __syncthreads();   // e_out done reading ET before P-writeback mutates it

    // ---- softmax + AV: wave wq owns head wq; P' written back to ET ----
    {
        const int h = wq;
        float vals[8];
        float rmax = -1e30f;
        #pragma unroll
        for (int k = 0; k < 8; ++k) {
            vals[k] = ET[h * ETS + k * 64 + lane];
            rmax = fmaxf(rmax, vals[k]);
        }
        #pragma unroll
        for (int off = 32; off >= 1; off >>= 1)
            rmax = fmaxf(rmax, __shfl_xor(rmax, off, 64));
        float sum = 0.f;
        #pragma unroll
        for (int k = 0; k < 8; ++k) {
            vals[k] = __expf(vals[k] - rmax);
            sum += vals[k];
        }
        #pragma unroll
        for (int off = 32; off >= 1; off >>= 1)
            sum += __shfl_xor(sum, off, 64);
        const float factor = dc[h] / sum;

        // write P' = P * factor back into ET (within-wave producer/consumer)
        #pragma unroll
        for (int k = 0; k < 8; ++k)
            ET[h * ETS + k * 64 + lane] = vals[k] * factor;

        // AV: lanes = 16 d x 4 m-groups; inner loop has NO exp
        const int ddx = lane & 15, mg = lane >> 4;
        const float* __restrict__ vb = Vw + ((size_t)(b * HH + h) * NN) * DKK;
        float av = 0.f;
        #pragma unroll 4
        for (int m = mg; m < NN; m += 4)
            av += ET[h * ETS + m] * vb[m * DKK + ddx];   // bcast LDS * coalesced V
        av += __shfl_xor(av, 16, 64);
        av += __shfl_xor(av, 32, 64);
        if (mg == 0) vout[h * DKK + ddx] = av;
    }
    __syncthreads();

    // ---- n_out = vout @ O_n ----
    if (t < DD) {
        float a3 = 0.f;
        #pragma unroll 4
        for (int d = 0; d < DD; ++d) a3 += vout[d] * O_n[d * DD + t];
        n_out[(size_t)bn * DD + t] = a3;
    }
    #undef STAGE_LOAD
    #undef STAGE_WRITE
    #undef STAGE_WRITE_ALL
}

extern "C" void kernel_launch(void* const* d_in, const int* in_sizes, int n_in,
                              void* d_out, int out_size, void* d_ws, size_t ws_size,
                              hipStream_t stream)
{
    const float* n_ptr = (const float*)d_in[0];
    const float* e     = (const float*)d_in[1];
    const float* W_qkv = (const float*)d_in[2];
    const float* O_n   = (const float*)d_in[3];
    const float* W_g   = (const float*)d_in[4];
    const float* W_e   = (const float*)d_in[5];
    const float* O_e   = (const float*)d_in[6];

    float* n_out = (float*)d_out;
    float* e_out = n_out + (size_t)BB * NN * DD;

    float* Qw   = (float*)d_ws;                          // 3 x 0.5MB
    float* Kw   = Qw + (size_t)BB * HH * NN * DKK;
    float* Vw   = Kw + (size_t)BB * HH * NN * DKK;
    float* WegT = Vw + (size_t)BB * HH * NN * DKK;       // 8KB

    qkv_kernel<<<BB * NN + 16, 128, 0, stream>>>(n_ptr, W_qkv, W_g, W_e,
                                                 Qw, Kw, Vw, WegT);
    eg_kernel<<<BB * NN, 512, 0, stream>>>(e, WegT, O_e, Qw, Kw, Vw, O_n,
                                           n_out, e_out);
}

// Round 19
// 161.420 us; speedup vs baseline: 1.8813x; 1.1033x over previous
//
#include <hip/hip_runtime.h>
#include <math.h>

#define BB 2
#define NN 512
#define DD 128
#define HH 8
#define DKK 16
#define ETS 516          // padded ET row stride (%32=4 -> conflict-free RMW)

typedef __attribute__((ext_vector_type(8))) short short8;
typedef __attribute__((ext_vector_type(4))) float f32x4;

__device__ __forceinline__ float dot4(float4 a, float4 b) {
    return a.x*b.x + a.y*b.y + a.z*b.z + a.w*b.w;
}
// RNE f32 -> bf16 pack (a in low, b in high)
__device__ __forceinline__ unsigned pk_bf16(float a, float b) {
    unsigned ua = __float_as_uint(a), ub = __float_as_uint(b);
    ua = (ua + 0x7FFFu + ((ua >> 16) & 1u)) >> 16;
    ub = (ub + 0x7FFFu + ((ub >> 16) & 1u)) >> 16;
    return ua | (ub << 16);
}

// ---------------- Kernel 1: QKV projection + W_egT staging ----------------
__global__ __launch_bounds__(128)
void qkv_kernel(const float* __restrict__ n_in,
                const float* __restrict__ W_qkv,
                const float* __restrict__ W_g,
                const float* __restrict__ W_e,
                float* __restrict__ Qw, float* __restrict__ Kw,
                float* __restrict__ Vw, float* __restrict__ WegT)
{
    const int bid = blockIdx.x;
    if (bid >= BB * NN) {                    // 16 trailing blocks: WegT[col][d]
        const int col = bid - BB * NN;
        const int t = threadIdx.x;
        WegT[col * DD + t] = (col < 8) ? W_e[t * HH + col]
                                       : W_g[t * HH + (col - 8)];
        return;
    }
    __shared__ float nrow[DD];
    const int bn = bid;
    const int b  = bn >> 9;
    const int nr = bn & 511;
    const int t  = threadIdx.x;
    nrow[t] = n_in[(size_t)bn * DD + t];
    __syncthreads();
    const int h = t >> 4, dk = t & 15;
    const size_t dst = ((size_t)(b * HH + h) * NN + nr) * DKK + dk;
    float accq = 0.f, acck = 0.f, accv = 0.f;
    #pragma unroll 8
    for (int d = 0; d < DD; ++d) {
        const float nv = nrow[d];
        const float* wr = W_qkv + (size_t)d * 3 * DD;
        accq += nv * wr[t];
        acck += nv * wr[t + 128];
        accv += nv * wr[t + 256];
    }
    Qw[dst] = accq;
    Kw[dst] = acck;
    Vw[dst] = accv;
}

// ---------------- Kernel 2: fused QK + E/G (MFMA direct-from-global) +
// e_out + softmax/AV + n_out. One block per (b,n), 512 threads = 8 waves.
// NO LDS staging of e, NO barriers in the main loop: each wave streams its
// own 16-row groups (rows g*16+c, 128B segments = full cache lines), packs
// f32->bf16 in regs, MFMAs, RMWs its disjoint ET rows. Waves free-run.
__global__ __attribute__((amdgpu_flat_work_group_size(512, 512),
                          amdgpu_waves_per_eu(2, 4)))
void eg_kernel(const float* __restrict__ e,
               const float* __restrict__ WegT,
               const float* __restrict__ O_e,
               const float* __restrict__ Qw,
               const float* __restrict__ Kw,
               const float* __restrict__ Vw,
               const float* __restrict__ O_n,
               float* __restrict__ n_out,
               float* __restrict__ e_out)
{
    __shared__ __align__(16) float ET[HH * ETS];     // 16.5KB persistent _E [h][m]
    __shared__ float Gred[64];
    __shared__ float dc[HH];
    __shared__ __align__(16) float vout[DD];

    const int t    = threadIdx.x;
    const int bn   = blockIdx.x;
    const int b    = bn >> 9;
    const int nr   = bn & 511;
    const int wq   = t >> 6;
    const int lane = t & 63;
    const int c    = lane & 15;      // MFMA C/D col (= W col / head)
    const int mq   = lane >> 4;      // C/D row group; also A/B k-group
    const int c4o  = t & 31;         // e_out float4 column
    const int mr0  = t >> 5;         // e_out row base 0..15

    const float4* __restrict__ e4    = (const float4*)e + (size_t)bn * NN * 32;
    const float4* __restrict__ WegT4 = (const float4*)WegT;

    // ---- B fragments: W[col=c][k] -> bf16, 4 k-steps (16 VGPR) ----
    short8 wB[4];
    #pragma unroll
    for (int kb = 0; kb < 4; ++kb) {
        const float4 wa = WegT4[c * 32 + kb * 8 + mq * 2];
        const float4 wb = WegT4[c * 32 + kb * 8 + mq * 2 + 1];
        uint4 u;
        u.x = pk_bf16(wa.x, wa.y); u.y = pk_bf16(wa.z, wa.w);
        u.z = pk_bf16(wb.x, wb.y); u.w = pk_bf16(wb.z, wb.w);
        wB[kb] = *(short8*)&u;
    }

    // ---- prologue: QK scores (K panel L2-resident) -> ET[h][m] ----
    {   // wave wq = head h
        const int h = wq;
        const float4* __restrict__ qp =
            (const float4*)(Qw + ((size_t)(b * HH + h) * NN + nr) * DKK);
        const float4 q0 = qp[0], q1 = qp[1], q2 = qp[2], q3 = qp[3];
        const float4* __restrict__ kb =
            (const float4*)(Kw + ((size_t)(b * HH + h) * NN) * DKK);
        #pragma unroll
        for (int k = 0; k < 8; ++k) {
            const int m = k * 64 + lane;
            float s = dot4(q0, kb[m * 4 + 0]) + dot4(q1, kb[m * 4 + 1])
                    + dot4(q2, kb[m * 4 + 2]) + dot4(q3, kb[m * 4 + 3]);
            s *= 0.25f;
            ET[h * ETS + m] = fminf(5.f, fmaxf(-5.f, s));
        }
    }
    __syncthreads();   // QK scores visible to all waves (cross-wave ET RMW)

    // ---- main loop: 4 groups per wave, ZERO barriers ----
    float ga0 = 0.f, ga1 = 0.f, ga2 = 0.f, ga3 = 0.f;

    #pragma unroll
    for (int j = 0; j < 4; ++j) {
        const int g    = wq + 8 * j;         // group 0..31 (disjoint rows)
        const int mrow = g * 16 + c;         // this lane's e-row

        // A fragments straight from global: 8 x dwordx4 (128B/row segments)
        const float4* __restrict__ ep = e4 + (size_t)mrow * 32 + mq * 2;
        const float4 ev0 = ep[0],  ev1 = ep[1];     // kb=0
        const float4 ev2 = ep[8],  ev3 = ep[9];     // kb=1
        const float4 ev4 = ep[16], ev5 = ep[17];    // kb=2
        const float4 ev6 = ep[24], ev7 = ep[25];    // kb=3

        f32x4 acc = {0.f, 0.f, 0.f, 0.f};
        {
            uint4 u;
            u.x = pk_bf16(ev0.x, ev0.y); u.y = pk_bf16(ev0.z, ev0.w);
            u.z = pk_bf16(ev1.x, ev1.y); u.w = pk_bf16(ev1.z, ev1.w);
            acc = __builtin_amdgcn_mfma_f32_16x16x32_bf16(*(short8*)&u, wB[0], acc, 0, 0, 0);
        }
        {
            uint4 u;
            u.x = pk_bf16(ev2.x, ev2.y); u.y = pk_bf16(ev2.z, ev2.w);
            u.z = pk_bf16(ev3.x, ev3.y); u.w = pk_bf16(ev3.z, ev3.w);
            acc = __builtin_amdgcn_mfma_f32_16x16x32_bf16(*(short8*)&u, wB[1], acc, 0, 0, 0);
        }
        {
            uint4 u;
            u.x = pk_bf16(ev4.x, ev4.y); u.y = pk_bf16(ev4.z, ev4.w);
            u.z = pk_bf16(ev5.x, ev5.y); u.w = pk_bf16(ev5.z, ev5.w);
            acc = __builtin_amdgcn_mfma_f32_16x16x32_bf16(*(short8*)&u, wB[2], acc, 0, 0, 0);
        }
        {
            uint4 u;
            u.x = pk_bf16(ev6.x, ev6.y); u.y = pk_bf16(ev6.z, ev6.w);
            u.z = pk_bf16(ev7.x, ev7.y); u.w = pk_bf16(ev7.z, ev7.w);
            acc = __builtin_amdgcn_mfma_f32_16x16x32_bf16(*(short8*)&u, wB[3], acc, 0, 0, 0);
        }

        // ---- epilogue: _E = acc + clamped_score (LDS RMW, rows disjoint
        // per wave; QK base synced above) / G accumulate ----
        const int mloc = g * 16 + mq * 4;
        if (c < 8) {
            float4 prev = *(float4*)&ET[c * ETS + mloc];
            prev.x += acc[0]; prev.y += acc[1];
            prev.z += acc[2]; prev.w += acc[3];
            *(float4*)&ET[c * ETS + mloc] = prev;
        } else {
            ga0 += 1.f / (1.f + __expf(-acc[0]));
            ga1 += 1.f / (1.f + __expf(-acc[1]));
            ga2 += 1.f / (1.f + __expf(-acc[2]));
            ga3 += 1.f / (1.f + __expf(-acc[3]));
        }
    }

    // ---- G reduction -> dyn_cent ----
    if (c >= 8) {
        float s = ga0 + ga1 + ga2 + ga3;
        s += __shfl_xor(s, 16, 64);
        s += __shfl_xor(s, 32, 64);
        if (lane < 16) Gred[wq * 8 + (c - 8)] = s;
    }
    __syncthreads();   // all ET RMWs + Gred visible
    if (t < 8) {
        float s = 0.f;
        #pragma unroll
        for (int w = 0; w < 8; ++w) s += Gred[w * 8 + t];
        dc[t] = log1pf(s);
    }
    __syncthreads();

    // ---- e_out phase: all 512 rows from persistent ET (R11-proven) ----
    {
        float4 oe[8];
        #pragma unroll
        for (int h = 0; h < 8; ++h)
            oe[h] = ((const float4*)O_e)[h * 32 + c4o];
        float4* __restrict__ out4 = (float4*)e_out + (size_t)bn * NN * 32;
        #pragma unroll 4
        for (int it = 0; it < 32; ++it) {
            const int m = mr0 + it * 16;
            float4 rr{0.f, 0.f, 0.f, 0.f};
            #pragma unroll
            for (int h = 0; h < 8; ++h) {
                const float ev = ET[h * ETS + m];   // broadcast read
                rr.x += ev * oe[h].x;
                rr.y += ev * oe[h].y;
                rr.z += ev * oe[h].z;
                rr.w += ev * oe[h].w;
            }
            out4[m * 32 + c4o] = rr;
        }
    }

    // ---- softmax + AV: wave wq owns head wq (R11-proven) ----
    {
        const int h = wq;
        float vals[8];
        float rmax = -1e30f;
        #pragma unroll
        for (int k = 0; k < 8; ++k) {
            vals[k] = ET[h * ETS + k * 64 + lane];
            rmax = fmaxf(rmax, vals[k]);
        }
        #pragma unroll
        for (int off = 32; off >= 1; off >>= 1)
            rmax = fmaxf(rmax, __shfl_xor(rmax, off, 64));
        float sum = 0.f;
        #pragma unroll
        for (int k = 0; k < 8; ++k) sum += __expf(vals[k] - rmax);
        #pragma unroll
        for (int off = 32; off >= 1; off >>= 1)
            sum += __shfl_xor(sum, off, 64);
        const float factor = dc[h] / sum;

        const int ddx = lane & 15, mg = lane >> 4;
        const float* __restrict__ vb = Vw + ((size_t)(b * HH + h) * NN) * DKK;
        float av = 0.f;
        #pragma unroll 4
        for (int m = mg; m < NN; m += 4) {
            const float p = __expf(ET[h * ETS + m] - rmax);
            av += p * vb[m * DKK + ddx];
        }
        av += __shfl_xor(av, 16, 64);
        av += __shfl_xor(av, 32, 64);
        if (mg == 0) vout[h * DKK + ddx] = av * factor;
    }
    __syncthreads();

    // ---- n_out = vout @ O_n ----
    if (t < DD) {
        float a3 = 0.f;
        #pragma unroll 4
        for (int d = 0; d < DD; ++d) a3 += vout[d] * O_n[d * DD + t];
        n_out[(size_t)bn * DD + t] = a3;
    }
}

extern "C" void kernel_launch(void* const* d_in, const int* in_sizes, int n_in,
                              void* d_out, int out_size, void* d_ws, size_t ws_size,
                              hipStream_t stream)
{
    const float* n_ptr = (const float*)d_in[0];
    const float* e     = (const float*)d_in[1];
    const float* W_qkv = (const float*)d_in[2];
    const float* O_n   = (const float*)d_in[3];
    const float* W_g   = (const float*)d_in[4];
    const float* W_e   = (const float*)d_in[5];
    const float* O_e   = (const float*)d_in[6];

    float* n_out = (float*)d_out;
    float* e_out = n_out + (size_t)BB * NN * DD;

    float* Qw   = (float*)d_ws;                          // 3 x 0.5MB
    float* Kw   = Qw + (size_t)BB * HH * NN * DKK;
    float* Vw   = Kw + (size_t)BB * HH * NN * DKK;
    float* WegT = Vw + (size_t)BB * HH * NN * DKK;       // 8KB

    qkv_kernel<<<BB * NN + 16, 128, 0, stream>>>(n_ptr, W_qkv, W_g, W_e,
                                                 Qw, Kw, Vw, WegT);
    eg_kernel<<<BB * NN, 512, 0, stream>>>(e, WegT, O_e, Qw, Kw, Vw, O_n,
                                           n_out, e_out);
}